// Round 10
// baseline (275.724 us; speedup 1.0000x reference)
//
#include <hip/hip_runtime.h>

typedef __attribute__((ext_vector_type(8))) __bf16 bf16x8;
typedef __attribute__((ext_vector_type(4))) float f32x4;

#define DEVINL __device__ __forceinline__

constexpr int BZ = 4;
constexpr int SEQ = 1024;
constexpr int DMODEL = 1024;
constexpr int NH = 16;
constexpr int HD = 64;               // dk = dv = 64
constexpr int MSLOT = 128;
constexpr int NT = BZ * SEQ;         // 4096 tokens
constexpr int SKM = SEQ + MSLOT;     // 1152 keys per batch
constexpr int VT_LD = BZ * SKM;      // 4608: leading dim of global V^T
constexpr float SCALE_M = 11.313708498984761f;   // sqrt(128)
constexpr float SCEXP = 0.18033688011112042f;    // (1/sqrt(dk)) * log2(e), folded into Q
// workspace offsets in bf16 (ushort) elements
constexpr size_t OF_WQT  = 0;
constexpr size_t OF_WKT  = OF_WQT  + (size_t)DMODEL * DMODEL;
constexpr size_t OF_WVT  = OF_WKT  + (size_t)DMODEL * DMODEL;
constexpr size_t OF_WOT  = OF_WVT  + (size_t)DMODEL * DMODEL;
constexpr size_t OF_QB   = OF_WOT  + (size_t)DMODEL * DMODEL;
constexpr size_t OF_KPR  = OF_QB   + (size_t)NT * DMODEL;
constexpr size_t OF_KMEM = OF_KPR  + (size_t)NT * DMODEL;
constexpr size_t OF_VTG  = OF_KMEM + (size_t)MSLOT * DMODEL;
constexpr size_t OF_AOUT = OF_VTG  + (size_t)DMODEL * VT_LD;

DEVINL unsigned short f2bf(float f) {
  union { float f; unsigned u; } v; v.f = f;
  unsigned r = v.u + 0x7FFF + ((v.u >> 16) & 1);   // RNE
  return (unsigned short)(r >> 16);
}

#if __has_builtin(__builtin_amdgcn_cvt_pk_bf16_f32)
DEVINL unsigned pack2(float a, float b) {
  auto t = __builtin_amdgcn_cvt_pk_bf16_f32(a, b);
  unsigned r; __builtin_memcpy(&r, &t, 4); return r;
}
#else
DEVINL unsigned pack2(float a, float b) {
  return (unsigned)f2bf(a) | ((unsigned)f2bf(b) << 16);
}
#endif

#if __has_builtin(__builtin_amdgcn_exp2f)
DEVINL float fast_exp2(float x) { return __builtin_amdgcn_exp2f(x); }
#else
DEVINL float fast_exp2(float x) { return exp2f(x); }
#endif

DEVINL f32x4 mfma16(bf16x8 a, bf16x8 b, f32x4 c) {
  return __builtin_amdgcn_mfma_f32_16x16x32_bf16(a, b, c, 0, 0, 0);
}

// async global -> LDS, 16 bytes per lane (global_load_lds_dwordx4)
DEVINL void gload16(const unsigned short* gp, unsigned short* lp) {
  __builtin_amdgcn_global_load_lds(
      (const __attribute__((address_space(1))) unsigned int*)(const void*)gp,
      (__attribute__((address_space(3))) unsigned int*)(void*)lp, 16, 0, 0);
}

DEVINL uint4 packf8(float4 a, float4 b) {
  union { unsigned u[4]; uint4 v; } o;
  o.u[0] = pack2(a.x, a.y); o.u[1] = pack2(a.z, a.w);
  o.u[2] = pack2(b.x, b.y); o.u[3] = pack2(b.z, b.w);
  return o.v;
}

// ---------------- prep kernel: weights transpose + memory slots only ----------------
// blocks [0,2048): W transpose+cvt (512/matrix); [2048,2560): Kmem; [2560,2688): mv->VtG
__global__ __launch_bounds__(256) void prep_all(
    const float* __restrict__ W0, const float* __restrict__ W1,
    const float* __restrict__ W2, const float* __restrict__ W3,
    const float* __restrict__ mk, const float* __restrict__ mv,
    unsigned short* __restrict__ d0, unsigned short* __restrict__ d1,
    unsigned short* __restrict__ d2, unsigned short* __restrict__ d3,
    unsigned short* __restrict__ Kmm, unsigned short* __restrict__ VtG) {
  __shared__ float t[32][65];
  const int tid = threadIdx.x;
  const int bid = blockIdx.x;
  if (bid < 2048) {
    const int z = bid >> 9, rem = bid & 511;
    const float* src = (z == 0) ? W0 : (z == 1) ? W1 : (z == 2) ? W2 : W3;
    unsigned short* dst = (z == 0) ? d0 : (z == 1) ? d1 : (z == 2) ? d2 : d3;
    const int n0 = (rem & 31) * 32, k0 = (rem >> 5) * 64;
    {
      int c = tid & 31, rg = tid >> 5;
#pragma unroll
      for (int rr = 0; rr < 8; ++rr)
        t[c][rg * 8 + rr] = src[(size_t)(k0 + rg * 8 + rr) * DMODEL + n0 + c];
    }
    __syncthreads();
    {
      int n = tid >> 3, ck = tid & 7;
      union { unsigned short u[8]; uint4 v; } o;
#pragma unroll
      for (int j = 0; j < 8; ++j) o.u[j] = f2bf(t[n][ck * 8 + j]);
      *(uint4*)(dst + (size_t)(n0 + n) * DMODEL + k0 + ck * 8) = o.v;
    }
  } else if (bid < 2560) {
    int i = (bid - 2048) * 256 + tid;
    Kmm[i] = f2bf(mk[i] * SCALE_M);
  } else {
    const int rel = bid - 2560;
    const int j0 = (rel & 3) * 32, c0 = (rel >> 2) * 32;
    const int tx = tid & 31, ty = tid >> 5;
#pragma unroll
    for (int r = 0; r < 4; ++r)
      t[ty + r * 8][tx] = mv[(size_t)(j0 + ty + r * 8) * DMODEL + c0 + tx];
    __syncthreads();
#pragma unroll
    for (int r = 0; r < 4; ++r) {
      int c = c0 + ty + r * 8;
      unsigned short vv = f2bf(t[tx][ty + r * 8] * SCALE_M);
#pragma unroll
      for (int bb = 0; bb < BZ; ++bb)
        VtG[(size_t)c * VT_LD + bb * SKM + SEQ + j0 + tx] = vv;
    }
  }
}

// ---------------- GEMM compute (BK=64 split column-half buffers, BM=128 BN=64) ----

DEVINL void gemm_compute(const unsigned short* B0, const unsigned short* B1,
                         const unsigned short* S0, const unsigned short* S1,
                         int wr, int wc, int quad, int l16, f32x4 acc[4][2]) {
#pragma unroll
  for (int hb = 0; hb < 2; ++hb) {
    const unsigned short* bl = hb ? B1 : B0;
    const unsigned short* sl = hb ? S1 : S0;
    bf16x8 af[4], bfr[2];
#pragma unroll
    for (int rb = 0; rb < 4; ++rb)
      af[rb] = *(const bf16x8*)(bl + (wr * 64 + rb * 16 + l16) * 32 + quad * 8);
#pragma unroll
    for (int cb = 0; cb < 2; ++cb)
      bfr[cb] = *(const bf16x8*)(sl + (wc * 32 + cb * 16 + l16) * 32 + quad * 8);
#pragma unroll
    for (int rb = 0; rb < 4; ++rb)
#pragma unroll
      for (int cb = 0; cb < 2; ++cb)
        acc[rb][cb] = mfma16(af[rb], bfr[cb], acc[rb][cb]);
  }
}

// merged Q/K/V projections, fp32 inputs converted in-flight during reg-prefetch
// staging (no global_load_lds: barrier drains only LDS writes; global latency
// overlaps compute — the attn-staging pattern). Q pre-scaled by SCEXP.
__global__ __launch_bounds__(256) void proj_qkv(
    const float* __restrict__ Qf, const float* __restrict__ Kf,
    const float* __restrict__ Vf, const unsigned short* __restrict__ Wqt,
    const unsigned short* __restrict__ Wkt, const unsigned short* __restrict__ Wvt,
    const float* __restrict__ bq, const float* __restrict__ bk,
    const float* __restrict__ bv, unsigned short* __restrict__ Qbp,
    unsigned short* __restrict__ Kprp, unsigned short* __restrict__ VtG) {
  __shared__ unsigned short Big0[128 * 32], Big1[128 * 32];
  __shared__ unsigned short Sm0[64 * 32], Sm1[64 * 32];
  const int tid = threadIdx.x;
  const int pid = blockIdx.x >> 9;
  const int idx = blockIdx.x & 511;
  const int w = tid >> 6, lane = tid & 63, quad = lane >> 4, l16 = lane & 15;
  const int wr = w >> 1, wc = w & 1;
  f32x4 acc[4][2] = {};

  const int br0 = tid >> 2, bs8 = (tid & 3) * 8;     // granule gi=0: row, k-suboffset
  const int br1 = 64 + (tid >> 2);                   // granule gi=1 row

  if (pid < 2) {
    const float* Af          = pid ? Kf : Qf;        // big operand: fp32 activations
    const unsigned short* Wt = pid ? Wkt : Wqt;      // small operand: bf16 weights
    const float* bias        = pid ? bk : bq;
    unsigned short* out      = pid ? Kprp : Qbp;
    const float osc          = pid ? 1.0f : SCEXP;
    const int m0 = (idx & 31) * 128, n0 = (idx >> 5) * 64;   // bid%8 = m%8
    const float* big = Af + (size_t)m0 * DMODEL;
    const unsigned short* sm = Wt + (size_t)n0 * DMODEL;

    float4 bp[8]; uint4 sp[2];
    auto pf = [&](int kt) {
      const int k0 = kt * 64;
#pragma unroll
      for (int hb = 0; hb < 2; ++hb) {
        const float* p0 = big + (size_t)br0 * DMODEL + k0 + hb * 32 + bs8;
        bp[hb * 4 + 0] = *(const float4*)p0;
        bp[hb * 4 + 1] = *(const float4*)(p0 + 4);
        const float* p1 = big + (size_t)br1 * DMODEL + k0 + hb * 32 + bs8;
        bp[hb * 4 + 2] = *(const float4*)p1;
        bp[hb * 4 + 3] = *(const float4*)(p1 + 4);
        sp[hb] = *(const uint4*)(sm + (size_t)br0 * DMODEL + k0 + hb * 32 + bs8);
      }
    };
    auto st = [&]() {
#pragma unroll
      for (int hb = 0; hb < 2; ++hb) {
        unsigned short* bl = hb ? Big1 : Big0;
        *(uint4*)(bl + tid * 8)         = packf8(bp[hb * 4 + 0], bp[hb * 4 + 1]);
        *(uint4*)(bl + (tid + 256) * 8) = packf8(bp[hb * 4 + 2], bp[hb * 4 + 3]);
        unsigned short* sl = hb ? Sm1 : Sm0;
        *(uint4*)(sl + tid * 8) = sp[hb];
      }
    };

    pf(0);
    for (int kt = 0; kt < 16; ++kt) {
      st();
      __syncthreads();                 // drains only LDS writes (lgkm)
      if (kt < 15) pf(kt + 1);         // global latency overlaps compute below
      gemm_compute(Big0, Big1, Sm0, Sm1, wr, wc, quad, l16, acc);
      __syncthreads();
    }
#pragma unroll
    for (int rb = 0; rb < 4; ++rb)
#pragma unroll
      for (int cb = 0; cb < 2; ++cb)
#pragma unroll
        for (int r = 0; r < 4; ++r) {
          int row = m0 + wr * 64 + rb * 16 + quad * 4 + r;
          int col = n0 + wc * 32 + cb * 16 + l16;
          out[(size_t)row * DMODEL + col] = f2bf((acc[rb][cb][r] + bias[col]) * osc);
        }
  } else {
    // V^T: big = Wvt rows (bf16), sm = Vf token rows (fp32, converted in-flight)
    const int t0 = (idx & 63) * 64, n0 = (idx >> 6) * 128;
    const unsigned short* big = Wvt + (size_t)n0 * DMODEL;
    const float* smf = Vf + (size_t)t0 * DMODEL;

    uint4 bpb[4]; float4 spf[4];
    auto pf = [&](int kt) {
      const int k0 = kt * 64;
#pragma unroll
      for (int hb = 0; hb < 2; ++hb) {
        bpb[hb * 2 + 0] = *(const uint4*)(big + (size_t)br0 * DMODEL + k0 + hb * 32 + bs8);
        bpb[hb * 2 + 1] = *(const uint4*)(big + (size_t)br1 * DMODEL + k0 + hb * 32 + bs8);
        const float* p = smf + (size_t)br0 * DMODEL + k0 + hb * 32 + bs8;
        spf[hb * 2 + 0] = *(const float4*)p;
        spf[hb * 2 + 1] = *(const float4*)(p + 4);
      }
    };
    auto st = [&]() {
#pragma unroll
      for (int hb = 0; hb < 2; ++hb) {
        unsigned short* bl = hb ? Big1 : Big0;
        *(uint4*)(bl + tid * 8)         = bpb[hb * 2 + 0];
        *(uint4*)(bl + (tid + 256) * 8) = bpb[hb * 2 + 1];
        unsigned short* sl = hb ? Sm1 : Sm0;
        *(uint4*)(sl + tid * 8) = packf8(spf[hb * 2 + 0], spf[hb * 2 + 1]);
      }
    };

    pf(0);
    for (int kt = 0; kt < 16; ++kt) {
      st();
      __syncthreads();
      if (kt < 15) pf(kt + 1);
      gemm_compute(Big0, Big1, Sm0, Sm1, wr, wc, quad, l16, acc);
      __syncthreads();
    }
#pragma unroll
    for (int rb = 0; rb < 4; ++rb)
#pragma unroll
      for (int cb = 0; cb < 2; ++cb)
#pragma unroll
        for (int r = 0; r < 4; ++r) {
          int n = n0 + wr * 64 + rb * 16 + quad * 4 + r;
          int tok = t0 + wc * 32 + cb * 16 + l16;
          int col = tok + (tok >> 10) * MSLOT;
          VtG[(size_t)n * VT_LD + col] = f2bf(acc[rb][cb][r] + bv[n]);
        }
  }
}

// output GEMM: BM=64 BN=64 BK=64, 1024 blocks = 4/CU; bid%8 = m%8 co-location.
__global__ __launch_bounds__(256) void gemm_out(const unsigned short* __restrict__ A,
                                                const unsigned short* __restrict__ Wt,
                                                const float* __restrict__ bias,
                                                float* __restrict__ Cout) {
  __shared__ unsigned short A0[64 * 32], A1[64 * 32];
  __shared__ unsigned short B0[64 * 32], B1[64 * 32];
  const int tid = threadIdx.x;
  const int idx = blockIdx.x;
  const int m0 = (idx & 63) * 64, n0 = (idx >> 6) * 64;    // bid%8 = m%8
  const int w = tid >> 6, lane = tid & 63, quad = lane >> 4, l16 = lane & 15;
  const int wr = w >> 1, wc = w & 1;
  f32x4 acc[2][2] = {};
  const unsigned short* rA = A + (size_t)m0 * DMODEL;
  const unsigned short* rB = Wt + (size_t)n0 * DMODEL;
  const int srow = tid >> 2, sslot = tid & 3;
  for (int kt = 0; kt < 16; ++kt) {
    const int k0 = kt * 64;
    gload16(rA + (size_t)srow * DMODEL + k0 + sslot * 8, A0 + tid * 8);
    gload16(rA + (size_t)srow * DMODEL + k0 + 32 + sslot * 8, A1 + tid * 8);
    gload16(rB + (size_t)srow * DMODEL + k0 + sslot * 8, B0 + tid * 8);
    gload16(rB + (size_t)srow * DMODEL + k0 + 32 + sslot * 8, B1 + tid * 8);
    __syncthreads();
#pragma unroll
    for (int hb = 0; hb < 2; ++hb) {
      const unsigned short* al = hb ? A1 : A0;
      const unsigned short* bl = hb ? B1 : B0;
      bf16x8 af[2], bfr[2];
#pragma unroll
      for (int rb = 0; rb < 2; ++rb)
        af[rb] = *(const bf16x8*)(al + (wr * 32 + rb * 16 + l16) * 32 + quad * 8);
#pragma unroll
      for (int cb = 0; cb < 2; ++cb)
        bfr[cb] = *(const bf16x8*)(bl + (wc * 32 + cb * 16 + l16) * 32 + quad * 8);
#pragma unroll
      for (int rb = 0; rb < 2; ++rb)
#pragma unroll
        for (int cb = 0; cb < 2; ++cb)
          acc[rb][cb] = mfma16(af[rb], bfr[cb], acc[rb][cb]);
    }
    __syncthreads();
  }
#pragma unroll
  for (int rb = 0; rb < 2; ++rb)
#pragma unroll
    for (int cb = 0; cb < 2; ++cb)
#pragma unroll
      for (int r = 0; r < 4; ++r) {
        int row = m0 + wr * 32 + rb * 16 + quad * 4 + r;
        int col = n0 + wc * 32 + cb * 16 + l16;
        Cout[(size_t)row * DMODEL + col] = acc[rb][cb][r] + bias[col];
      }
}

// ---------------- flash attention v4 (unchanged from R9) ----------------
__global__ __launch_bounds__(256) void attn_kernel(const unsigned short* __restrict__ Qb,
                                                   const unsigned short* __restrict__ Kproj,
                                                   const unsigned short* __restrict__ Kmem,
                                                   const unsigned short* __restrict__ VtG,
                                                   unsigned short* __restrict__ Aout) {
  __shared__ unsigned short Ks[2][64 * 64];
  __shared__ unsigned short Vs[2][64 * 64];
  __shared__ unsigned short Pl[4 * 16 * 64];    // per-wave P[q][key], same swizzle
  const int tid = threadIdx.x;
  const int bh = blockIdx.x & 63, qb = blockIdx.x >> 6;
  const int b = bh & 3, h = bh >> 2;
  const int w = tid >> 6, lane = tid & 63, quad = lane >> 4, l16 = lane & 15;
  const int token0 = b * SEQ + qb * 64 + w * 16;
  unsigned short* Pw = Pl + w * 16 * 64;
  const int lx = l16 & 7;

  const int row0 = tid >> 3, slot0 = tid & 7;
  const int g1 = tid + 256;
  const int row1 = g1 >> 3, slot1 = g1 & 7;
  const int loff0 = row0 * 64 + (slot0 ^ (row0 & 7)) * 8;
  const int loff1 = row1 * 64 + (slot1 ^ (row1 & 7)) * 8;

  auto kbase = [&](int tile) -> const unsigned short* {
    return (tile < 16) ? Kproj + (size_t)(b * SEQ + tile * 64) * DMODEL + h * HD
                       : Kmem + (size_t)((tile - 16) * 64) * DMODEL + h * HD;
  };
  auto vbase = [&](int tile) -> const unsigned short* {
    int c0 = (tile < 16) ? b * SKM + tile * 64 : b * SKM + SEQ + (tile - 16) * 64;
    return VtG + (size_t)(h * HD) * VT_LD + c0;
  };

  bf16x8 qf[2];   // B-operand: Q[n=l16][k=quad*8+j(+32t)] (pre-scaled by SCEXP)
#pragma unroll
  for (int t = 0; t < 2; ++t)
    qf[t] = *(const bf16x8*)(Qb + (size_t)(token0 + l16) * DMODEL + h * HD + t * 32 + quad * 8);

  bf16x8 ones;
  {
    union { unsigned short u[8]; bf16x8 v; } one8;
#pragma unroll
    for (int i = 0; i < 8; ++i) one8.u[i] = 0x3F80;   // bf16 1.0
    ones = one8.v;
  }

  f32x4 O[4] = {};
  f32x4 Lacc = {};

  uint4 kr0, kr1, vr0, vr1;
  {
    const unsigned short* kp = kbase(0);
    const unsigned short* vp = vbase(0);
    kr0 = *(const uint4*)(kp + (size_t)row0 * DMODEL + slot0 * 8);
    kr1 = *(const uint4*)(kp + (size_t)row1 * DMODEL + slot1 * 8);
    vr0 = *(const uint4*)(vp + (size_t)row0 * VT_LD + slot0 * 8);
    vr1 = *(const uint4*)(vp + (size_t)row1 * VT_LD + slot1 * 8);
  }
  *(uint4*)(Ks[0] + loff0) = kr0;
  *(uint4*)(Ks[0] + loff1) = kr1;
  *(uint4*)(Vs[0] + loff0) = vr0;
  *(uint4*)(Vs[0] + loff1) = vr1;
  __syncthreads();

  for (int tile = 0; tile < 18; ++tile) {
    const int cur = tile & 1;
    if (tile < 17) {
      const unsigned short* kp = kbase(tile + 1);
      const unsigned short* vp = vbase(tile + 1);
      kr0 = *(const uint4*)(kp + (size_t)row0 * DMODEL + slot0 * 8);
      kr1 = *(const uint4*)(kp + (size_t)row1 * DMODEL + slot1 * 8);
      vr0 = *(const uint4*)(vp + (size_t)row0 * VT_LD + slot0 * 8);
      vr1 = *(const uint4*)(vp + (size_t)row1 * VT_LD + slot1 * 8);
    }

    f32x4 sc[4] = {};
#pragma unroll
    for (int c = 0; c < 4; ++c)
#pragma unroll
      for (int t = 0; t < 2; ++t) {
        bf16x8 kb = *(const bf16x8*)(Ks[cur] + (c * 16 + l16) * 64 +
                                     ((t * 4 + quad) ^ lx) * 8);
        sc[c] = mfma16(kb, qf[t], sc[c]);
      }

#pragma unroll
    for (int c = 0; c < 4; ++c) {
      float p0 = fast_exp2(sc[c][0]);
      float p1 = fast_exp2(sc[c][1]);
      float p2 = fast_exp2(sc[c][2]);
      float p3 = fast_exp2(sc[c][3]);
      union { unsigned u[2]; } pk;
      pk.u[0] = pack2(p0, p1);
      pk.u[1] = pack2(p2, p3);
      *(uint2*)(Pw + l16 * 64 + ((2 * c + (quad >> 1)) ^ lx) * 8 + (quad & 1) * 4) =
          *(uint2*)pk.u;
    }
    __builtin_amdgcn_wave_barrier();   // order DS write -> DS read (wave-local)

#pragma unroll
    for (int t2 = 0; t2 < 2; ++t2) {
      bf16x8 pa = *(const bf16x8*)(Pw + l16 * 64 + ((t2 * 4 + quad) ^ lx) * 8);
      Lacc = mfma16(pa, ones, Lacc);   // row sums of P: lsum[q=quad*4+r]
#pragma unroll
      for (int c2 = 0; c2 < 4; ++c2) {
        bf16x8 vb = *(const bf16x8*)(Vs[cur] + (c2 * 16 + l16) * 64 +
                                     ((t2 * 4 + quad) ^ lx) * 8);
        O[c2] = mfma16(pa, vb, O[c2]);
      }
    }

    if (tile < 17) {
      *(uint4*)(Ks[cur ^ 1] + loff0) = kr0;
      *(uint4*)(Ks[cur ^ 1] + loff1) = kr1;
      *(uint4*)(Vs[cur ^ 1] + loff0) = vr0;
      *(uint4*)(Vs[cur ^ 1] + loff1) = vr1;
    }
    __syncthreads();
  }

#pragma unroll
  for (int r = 0; r < 4; ++r) {
    float inv = 1.0f / Lacc[r];
#pragma unroll
    for (int c2 = 0; c2 < 4; ++c2)
      Aout[(size_t)(token0 + quad * 4 + r) * DMODEL + h * HD + c2 * 16 + l16] =
          f2bf(O[c2][r] * inv);
  }
}

// ---------------- launch ----------------
extern "C" void kernel_launch(void* const* d_in, const int* in_sizes, int n_in,
                              void* d_out, int out_size, void* d_ws, size_t ws_size,
                              hipStream_t stream) {
  const float* queries = (const float*)d_in[0];
  const float* keys    = (const float*)d_in[1];
  const float* values  = (const float*)d_in[2];
  const float* Wq = (const float*)d_in[3];
  const float* bq = (const float*)d_in[4];
  const float* Wk = (const float*)d_in[5];
  const float* bk = (const float*)d_in[6];
  const float* Wv = (const float*)d_in[7];
  const float* bv = (const float*)d_in[8];
  const float* Wo = (const float*)d_in[9];
  const float* bo = (const float*)d_in[10];
  const float* mk = (const float*)d_in[11];
  const float* mv = (const float*)d_in[12];

  unsigned short* ws = (unsigned short*)d_ws;
  unsigned short* Wqt  = ws + OF_WQT;
  unsigned short* Wkt  = ws + OF_WKT;
  unsigned short* Wvt  = ws + OF_WVT;
  unsigned short* Wot  = ws + OF_WOT;
  unsigned short* Qbp  = ws + OF_QB;
  unsigned short* Kprp = ws + OF_KPR;
  unsigned short* Kmm  = ws + OF_KMEM;
  unsigned short* VtGp = ws + OF_VTG;
  unsigned short* Aoutp = ws + OF_AOUT;

  prep_all<<<2688, 256, 0, stream>>>(Wq, Wk, Wv, Wo, mk, mv,
                                     Wqt, Wkt, Wvt, Wot, Kmm, VtGp);

  proj_qkv<<<1536, 256, 0, stream>>>(queries, keys, values, Wqt, Wkt, Wvt,
                                     bq, bk, bv, Qbp, Kprp, VtGp);

  attn_kernel<<<1024, 256, 0, stream>>>(Qbp, Kprp, Kmm, VtGp, Aoutp);

  gemm_out<<<1024, 256, 0, stream>>>(Aoutp, Wot, bo, (float*)d_out);
}